// Round 4
// baseline (267.972 us; speedup 1.0000x reference)
//
#include <hip/hip_runtime.h>
#include <hip/hip_bf16.h>

#define B_N 8192
#define D_K 256
#define MARGIN 0.3f

typedef float f32x4 __attribute__((ext_vector_type(4)));
typedef short s16x8 __attribute__((ext_vector_type(8)));

// Order-preserving float->uint for atomicMax/atomicMin on floats.
__device__ __forceinline__ unsigned fkey(float f) {
    unsigned u = __float_as_uint(f);
    return (u & 0x80000000u) ? ~u : (u | 0x80000000u);
}
__device__ __forceinline__ float kval(unsigned k) {
    return (k & 0x80000000u) ? __uint_as_float(k ^ 0x80000000u)
                             : __uint_as_float(~k);
}
__device__ __forceinline__ unsigned short bfbits(float f) {
    __hip_bfloat16 h = __float2bfloat16(f);
    return *reinterpret_cast<unsigned short*>(&h);
}

// ---- kernel 1: norms + bf16 hi/lo split (interleaved layout) + init ------
// Xp layout: [row][chunk=k/8][hi:8 shorts | lo:8 shorts]  (row stride 512 shorts)
__global__ __launch_bounds__(256) void prep_kernel(const float* __restrict__ X,
        float* __restrict__ sq, unsigned* __restrict__ apk,
        unsigned* __restrict__ ank, unsigned short* __restrict__ Xp,
        float* __restrict__ acc2) {
    int row  = (blockIdx.x << 2) + (threadIdx.x >> 6);
    int lane = threadIdx.x & 63;
    const float4 v = reinterpret_cast<const float4*>(X + (size_t)row * D_K)[lane];
    float s = v.x * v.x + v.y * v.y + v.z * v.z + v.w * v.w;

    float xs[4] = {v.x, v.y, v.z, v.w};
    ushort4 hv, lv;
    unsigned short* hp = &hv.x; unsigned short* lp = &lv.x;
    #pragma unroll
    for (int i = 0; i < 4; ++i) {
        __hip_bfloat16 h = __float2bfloat16(xs[i]);
        hp[i] = *reinterpret_cast<unsigned short*>(&h);
        lp[i] = bfbits(xs[i] - __bfloat162float(h));
    }
    // thread covers k in [4*lane, 4*lane+4) -> chunk = lane>>1, half = lane&1
    size_t base = (size_t)row * 512 + (lane >> 1) * 16 + (lane & 1) * 4;
    *reinterpret_cast<ushort4*>(Xp + base)     = hv;   // hi half
    *reinterpret_cast<ushort4*>(Xp + base + 8) = lv;   // lo half

    #pragma unroll
    for (int o = 32; o > 0; o >>= 1) s += __shfl_down(s, o, 64);
    if (lane == 0) {
        sq[row]  = s;
        apk[row] = 0u;           // <= fkey(-inf)
        ank[row] = 0xFFFFFFFFu;  // >= fkey(+inf)
    }
    if (blockIdx.x == 0 && threadIdx.x == 0) { acc2[0] = 0.f; acc2[1] = 0.f; }
}

// ---- kernel 2: barrier-free MFMA dist + fused mining (no LDS) ------------
#define BM 128
#define BN 128

__global__ __launch_bounds__(256, 3) void dist_kernel(
        const unsigned short* __restrict__ Xp,
        const int* __restrict__ tgt, const float* __restrict__ sq,
        unsigned* __restrict__ apk, unsigned* __restrict__ ank) {
    if (blockIdx.y > blockIdx.x) return;   // upper-triangular blocks only
    const int bm = blockIdx.y * BM;        // bm <= bn
    const int bn = blockIdx.x * BN;

    const int t    = threadIdx.x;
    const int lane = t & 63;
    const int wave = t >> 6;
    const int wrow = (wave >> 1) * 64;
    const int wcol = (wave & 1) * 64;
    const int fr   = lane & 15;
    const int quad = lane >> 4;

    // per-lane base pointers (shorts): row*512 + quad_chunk*16
    const unsigned short* arow[4];
    const unsigned short* brow[4];
    #pragma unroll
    for (int mi = 0; mi < 4; ++mi)
        arow[mi] = Xp + (size_t)(bm + wrow + mi * 16 + fr) * 512 + quad * 16;
    #pragma unroll
    for (int ni = 0; ni < 4; ++ni)
        brow[ni] = Xp + (size_t)(bn + wcol + ni * 16 + fr) * 512 + quad * 16;

    f32x4 acc[4][4];
    #pragma unroll
    for (int i = 0; i < 4; ++i)
        #pragma unroll
        for (int j = 0; j < 4; ++j) acc[i][j] = (f32x4){0.f, 0.f, 0.f, 0.f};

    // chunk base: 4 chunks (K=32) per iter, 32 chunks total -> cb = 0,4,...,28
    #pragma unroll 1
    for (int cb = 0; cb < 32; cb += 4) {
        s16x8 a_hi[4], a_lo[4], b_hi[4], b_lo[4];
        #pragma unroll
        for (int mi = 0; mi < 4; ++mi) {
            const s16x8* p = reinterpret_cast<const s16x8*>(arow[mi] + cb * 16);
            a_hi[mi] = p[0]; a_lo[mi] = p[1];
        }
        #pragma unroll
        for (int ni = 0; ni < 4; ++ni) {
            const s16x8* p = reinterpret_cast<const s16x8*>(brow[ni] + cb * 16);
            b_hi[ni] = p[0]; b_lo[ni] = p[1];
        }
        #pragma unroll
        for (int mi = 0; mi < 4; ++mi)
            #pragma unroll
            for (int ni = 0; ni < 4; ++ni) {
                acc[mi][ni] = __builtin_amdgcn_mfma_f32_16x16x32_bf16(
                    a_hi[mi], b_hi[ni], acc[mi][ni], 0, 0, 0);
                acc[mi][ni] = __builtin_amdgcn_mfma_f32_16x16x32_bf16(
                    a_hi[mi], b_lo[ni], acc[mi][ni], 0, 0, 0);
                acc[mi][ni] = __builtin_amdgcn_mfma_f32_16x16x32_bf16(
                    a_lo[mi], b_hi[ni], acc[mi][ni], 0, 0, 0);
            }
    }

    // -------- epilogue: dist + row mining + col mining ---------------------
    const float INF = __int_as_float(0x7f800000);
    int   ct[4]; float csq[4];
    #pragma unroll
    for (int ni = 0; ni < 4; ++ni) {
        int c = bn + wcol + ni * 16 + fr;
        ct[ni] = tgt[c]; csq[ni] = sq[c];
    }
    float cap[4], can[4];
    #pragma unroll
    for (int ni = 0; ni < 4; ++ni) { cap[ni] = -INF; can[ni] = INF; }

    #pragma unroll
    for (int mi = 0; mi < 4; ++mi) {
        #pragma unroll
        for (int reg = 0; reg < 4; ++reg) {
            int rl = wrow + mi * 16 + quad * 4 + reg;
            int rt = tgt[bm + rl]; float rsq = sq[bm + rl];
            float rap = -INF, ran = INF;
            #pragma unroll
            for (int ni = 0; ni < 4; ++ni) {
                float d = rsq + csq[ni] - 2.f * acc[mi][ni][reg];
                bool pos = (rt == ct[ni]);
                if (pos) { rap = fmaxf(rap, d); cap[ni] = fmaxf(cap[ni], d); }
                else     { ran = fminf(ran, d); can[ni] = fminf(can[ni], d); }
            }
            #pragma unroll
            for (int o = 1; o < 16; o <<= 1) {
                rap = fmaxf(rap, __shfl_xor(rap, o, 64));
                ran = fminf(ran, __shfl_xor(ran, o, 64));
            }
            if (fr == 0) {
                atomicMax(&apk[bm + rl], fkey(rap));
                atomicMin(&ank[bm + rl], fkey(ran));
            }
        }
    }
    #pragma unroll
    for (int ni = 0; ni < 4; ++ni) {
        #pragma unroll
        for (int o = 16; o < 64; o <<= 1) {
            cap[ni] = fmaxf(cap[ni], __shfl_xor(cap[ni], o, 64));
            can[ni] = fminf(can[ni], __shfl_xor(can[ni], o, 64));
        }
    }
    if (lane < 16) {
        #pragma unroll
        for (int ni = 0; ni < 4; ++ni) {
            int c = bn + wcol + ni * 16 + lane;
            atomicMax(&apk[c], fkey(cap[ni]));
            atomicMin(&ank[c], fkey(can[ni]));
        }
    }
}

// ---- kernel 3a: partial loss/prec sums (32 blocks) ------------------------
__global__ __launch_bounds__(256) void final1_kernel(const unsigned* __restrict__ apk,
        const unsigned* __restrict__ ank, float* __restrict__ acc2) {
    __shared__ float s_sum[4], s_cnt[4];
    int i = blockIdx.x * 256 + threadIdx.x;
    float ap = kval(apk[i]);
    float an = kval(ank[i]);
    float v  = ap - an + MARGIN;
    float sum = v > 0.f ? v : 0.f;
    float cnt = an > ap ? 1.f : 0.f;
    #pragma unroll
    for (int o = 32; o > 0; o >>= 1) {
        sum += __shfl_down(sum, o, 64);
        cnt += __shfl_down(cnt, o, 64);
    }
    int wave = threadIdx.x >> 6, lane = threadIdx.x & 63;
    if (lane == 0) { s_sum[wave] = sum; s_cnt[wave] = cnt; }
    __syncthreads();
    if (threadIdx.x == 0) {
        float ts = 0.f, tc = 0.f;
        #pragma unroll
        for (int w = 0; w < 4; ++w) { ts += s_sum[w]; tc += s_cnt[w]; }
        atomicAdd(&acc2[0], ts);
        atomicAdd(&acc2[1], tc);
    }
}

// ---- kernel 3b: finalize --------------------------------------------------
__global__ void final2_kernel(const float* __restrict__ acc2,
                              float* __restrict__ out) {
    if (threadIdx.x == 0) {
        out[0] = acc2[0] / (float)B_N;
        out[1] = acc2[1] / (float)B_N;
    }
}

extern "C" void kernel_launch(void* const* d_in, const int* in_sizes, int n_in,
                              void* d_out, int out_size, void* d_ws, size_t ws_size,
                              hipStream_t stream) {
    const float* X   = (const float*)d_in[0];
    const int*   tgt = (const int*)d_in[1];

    char* ws = (char*)d_ws;
    float*          sq   = (float*)ws;                    // 32 KB
    unsigned*       apk  = (unsigned*)(ws + 32768);       // 32 KB
    unsigned*       ank  = (unsigned*)(ws + 65536);       // 32 KB
    float*          acc2 = (float*)(ws + 98304);          // 8 B
    unsigned short* Xp   = (unsigned short*)(ws + 131072);// 8 MB

    float* out = (float*)d_out;

    prep_kernel<<<B_N / 4, 256, 0, stream>>>(X, sq, apk, ank, Xp, acc2);
    dist_kernel<<<dim3(B_N / BN, B_N / BM), 256, 0, stream>>>(Xp, tgt, sq, apk, ank);
    final1_kernel<<<B_N / 256, 256, 0, stream>>>(apk, ank, acc2);
    final2_kernel<<<1, 64, 0, stream>>>(acc2, out);
}

// Round 5
// 227.906 us; speedup vs baseline: 1.1758x; 1.1758x over previous
//
#include <hip/hip_runtime.h>
#include <hip/hip_bf16.h>

#define B_N 8192
#define D_K 256
#define MARGIN 0.3f

typedef float f32x4 __attribute__((ext_vector_type(4)));
typedef short s16x8 __attribute__((ext_vector_type(8)));

// Order-preserving float->uint for atomicMax/atomicMin on floats.
__device__ __forceinline__ unsigned fkey(float f) {
    unsigned u = __float_as_uint(f);
    return (u & 0x80000000u) ? ~u : (u | 0x80000000u);
}
__device__ __forceinline__ float kval(unsigned k) {
    return (k & 0x80000000u) ? __uint_as_float(k ^ 0x80000000u)
                             : __uint_as_float(~k);
}
__device__ __forceinline__ unsigned short bfbits(float f) {
    __hip_bfloat16 h = __float2bfloat16(f);
    return *reinterpret_cast<unsigned short*>(&h);
}

// ---- kernel 1: norms + bf16 hi/lo split (interleaved layout) + init ------
// Xp layout: [row][chunk=k/8][hi:8 shorts | lo:8 shorts]  (row stride 512 shorts)
__global__ __launch_bounds__(256) void prep_kernel(const float* __restrict__ X,
        float* __restrict__ sq, unsigned* __restrict__ apk,
        unsigned* __restrict__ ank, unsigned short* __restrict__ Xp,
        float* __restrict__ acc2) {
    int row  = (blockIdx.x << 2) + (threadIdx.x >> 6);
    int lane = threadIdx.x & 63;
    const float4 v = reinterpret_cast<const float4*>(X + (size_t)row * D_K)[lane];
    float s = v.x * v.x + v.y * v.y + v.z * v.z + v.w * v.w;

    float xs[4] = {v.x, v.y, v.z, v.w};
    ushort4 hv, lv;
    unsigned short* hp = &hv.x; unsigned short* lp = &lv.x;
    #pragma unroll
    for (int i = 0; i < 4; ++i) {
        __hip_bfloat16 h = __float2bfloat16(xs[i]);
        hp[i] = *reinterpret_cast<unsigned short*>(&h);
        lp[i] = bfbits(xs[i] - __bfloat162float(h));
    }
    size_t base = (size_t)row * 512 + (lane >> 1) * 16 + (lane & 1) * 4;
    *reinterpret_cast<ushort4*>(Xp + base)     = hv;   // hi half
    *reinterpret_cast<ushort4*>(Xp + base + 8) = lv;   // lo half

    #pragma unroll
    for (int o = 32; o > 0; o >>= 1) s += __shfl_down(s, o, 64);
    if (lane == 0) {
        sq[row]  = s;
        apk[row] = 0u;           // <= fkey(-inf)
        ank[row] = 0xFFFFFFFFu;  // >= fkey(+inf)
    }
    if (blockIdx.x == 0 && threadIdx.x == 0) {
        acc2[0] = 0.f; acc2[1] = 0.f;
        reinterpret_cast<unsigned*>(acc2)[2] = 0u;   // ticket counter
    }
}

// ---- kernel 2: barrier-free MFMA dist, register-pipelined -----------------
#define BM 128
#define BN 128

#define LOAD_FRAGS(b, cbase)                                                  \
    {                                                                         \
        _Pragma("unroll")                                                     \
        for (int mi = 0; mi < 4; ++mi) {                                      \
            const s16x8* p =                                                  \
                reinterpret_cast<const s16x8*>(arow[mi] + (cbase) * 16);      \
            a_hi[b][mi] = p[0]; a_lo[b][mi] = p[1];                           \
        }                                                                     \
        _Pragma("unroll")                                                     \
        for (int ni = 0; ni < 4; ++ni) {                                      \
            const s16x8* p =                                                  \
                reinterpret_cast<const s16x8*>(brow[ni] + (cbase) * 16);      \
            b_hi[b][ni] = p[0]; b_lo[b][ni] = p[1];                           \
        }                                                                     \
    }

__global__ __launch_bounds__(256, 2) void dist_kernel(
        const unsigned short* __restrict__ Xp,
        const int* __restrict__ tgt, const float* __restrict__ sq,
        unsigned* __restrict__ apk, unsigned* __restrict__ ank) {
    // triangular decode: blockIdx.x -> (bx, by), by <= bx
    int tt = blockIdx.x;
    int bx = (int)((sqrtf(8.f * (float)tt + 1.f) - 1.f) * 0.5f);
    while ((bx + 1) * (bx + 2) / 2 <= tt) ++bx;
    while (bx * (bx + 1) / 2 > tt) --bx;
    int by = tt - bx * (bx + 1) / 2;
    const int bm = by * BM;   // bm <= bn
    const int bn = bx * BN;

    const int t    = threadIdx.x;
    const int lane = t & 63;
    const int wave = t >> 6;
    const int wrow = (wave >> 1) * 64;
    const int wcol = (wave & 1) * 64;
    const int fr   = lane & 15;
    const int quad = lane >> 4;

    const unsigned short* arow[4];
    const unsigned short* brow[4];
    #pragma unroll
    for (int mi = 0; mi < 4; ++mi)
        arow[mi] = Xp + (size_t)(bm + wrow + mi * 16 + fr) * 512 + quad * 16;
    #pragma unroll
    for (int ni = 0; ni < 4; ++ni)
        brow[ni] = Xp + (size_t)(bn + wcol + ni * 16 + fr) * 512 + quad * 16;

    f32x4 acc[4][4];
    #pragma unroll
    for (int i = 0; i < 4; ++i)
        #pragma unroll
        for (int j = 0; j < 4; ++j) acc[i][j] = (f32x4){0.f, 0.f, 0.f, 0.f};

    s16x8 a_hi[2][4], a_lo[2][4], b_hi[2][4], b_lo[2][4];
    LOAD_FRAGS(0, 0)

    // 8 K-iters (K=32 each, chunk base 4i), fully unrolled, 2-deep reg pipeline
    #pragma unroll
    for (int i = 0; i < 8; ++i) {
        const int cur = i & 1;
        if (i < 7) LOAD_FRAGS(cur ^ 1, (i + 1) * 4)
        #pragma unroll
        for (int mi = 0; mi < 4; ++mi)
            #pragma unroll
            for (int ni = 0; ni < 4; ++ni) {
                acc[mi][ni] = __builtin_amdgcn_mfma_f32_16x16x32_bf16(
                    a_hi[cur][mi], b_hi[cur][ni], acc[mi][ni], 0, 0, 0);
                acc[mi][ni] = __builtin_amdgcn_mfma_f32_16x16x32_bf16(
                    a_hi[cur][mi], b_lo[cur][ni], acc[mi][ni], 0, 0, 0);
                acc[mi][ni] = __builtin_amdgcn_mfma_f32_16x16x32_bf16(
                    a_lo[cur][mi], b_hi[cur][ni], acc[mi][ni], 0, 0, 0);
            }
    }

    // -------- epilogue: dist + row mining + col mining ---------------------
    const float INF = __int_as_float(0x7f800000);
    int   ct[4]; float csq[4];
    #pragma unroll
    for (int ni = 0; ni < 4; ++ni) {
        int c = bn + wcol + ni * 16 + fr;
        ct[ni] = tgt[c]; csq[ni] = sq[c];
    }
    float cap[4], can[4];
    #pragma unroll
    for (int ni = 0; ni < 4; ++ni) { cap[ni] = -INF; can[ni] = INF; }

    #pragma unroll
    for (int mi = 0; mi < 4; ++mi) {
        #pragma unroll
        for (int reg = 0; reg < 4; ++reg) {
            int rl = wrow + mi * 16 + quad * 4 + reg;
            int rt = tgt[bm + rl]; float rsq = sq[bm + rl];
            float rap = -INF, ran = INF;
            #pragma unroll
            for (int ni = 0; ni < 4; ++ni) {
                float d = rsq + csq[ni] - 2.f * acc[mi][ni][reg];
                bool pos = (rt == ct[ni]);
                if (pos) { rap = fmaxf(rap, d); cap[ni] = fmaxf(cap[ni], d); }
                else     { ran = fminf(ran, d); can[ni] = fminf(can[ni], d); }
            }
            #pragma unroll
            for (int o = 1; o < 16; o <<= 1) {
                rap = fmaxf(rap, __shfl_xor(rap, o, 64));
                ran = fminf(ran, __shfl_xor(ran, o, 64));
            }
            if (fr == 0) {
                atomicMax(&apk[bm + rl], fkey(rap));
                atomicMin(&ank[bm + rl], fkey(ran));
            }
        }
    }
    #pragma unroll
    for (int ni = 0; ni < 4; ++ni) {
        #pragma unroll
        for (int o = 16; o < 64; o <<= 1) {
            cap[ni] = fmaxf(cap[ni], __shfl_xor(cap[ni], o, 64));
            can[ni] = fminf(can[ni], __shfl_xor(can[ni], o, 64));
        }
    }
    if (lane < 16) {
        #pragma unroll
        for (int ni = 0; ni < 4; ++ni) {
            int c = bn + wcol + ni * 16 + lane;
            atomicMax(&apk[c], fkey(cap[ni]));
            atomicMin(&ank[c], fkey(can[ni]));
        }
    }
}

// ---- kernel 3: loss/prec partial sums + last-block finalize ---------------
__global__ __launch_bounds__(256) void final_kernel(const unsigned* __restrict__ apk,
        const unsigned* __restrict__ ank, float* __restrict__ acc2,
        float* __restrict__ out) {
    __shared__ float s_sum[4], s_cnt[4];
    int i = blockIdx.x * 256 + threadIdx.x;
    float ap = kval(apk[i]);
    float an = kval(ank[i]);
    float v  = ap - an + MARGIN;
    float sum = v > 0.f ? v : 0.f;
    float cnt = an > ap ? 1.f : 0.f;
    #pragma unroll
    for (int o = 32; o > 0; o >>= 1) {
        sum += __shfl_down(sum, o, 64);
        cnt += __shfl_down(cnt, o, 64);
    }
    int wave = threadIdx.x >> 6, lane = threadIdx.x & 63;
    if (lane == 0) { s_sum[wave] = sum; s_cnt[wave] = cnt; }
    __syncthreads();
    if (threadIdx.x == 0) {
        float ts = 0.f, tc = 0.f;
        #pragma unroll
        for (int w = 0; w < 4; ++w) { ts += s_sum[w]; tc += s_cnt[w]; }
        atomicAdd(&acc2[0], ts);
        atomicAdd(&acc2[1], tc);
        __threadfence();
        unsigned ticket = atomicAdd(reinterpret_cast<unsigned*>(acc2) + 2, 1u);
        if (ticket == gridDim.x - 1) {
            // device-scope atomic reads (coherent across XCDs)
            float fs = atomicAdd(&acc2[0], 0.f);
            float fc = atomicAdd(&acc2[1], 0.f);
            out[0] = fs / (float)B_N;
            out[1] = fc / (float)B_N;
        }
    }
}

extern "C" void kernel_launch(void* const* d_in, const int* in_sizes, int n_in,
                              void* d_out, int out_size, void* d_ws, size_t ws_size,
                              hipStream_t stream) {
    const float* X   = (const float*)d_in[0];
    const int*   tgt = (const int*)d_in[1];

    char* ws = (char*)d_ws;
    float*          sq   = (float*)ws;                    // 32 KB
    unsigned*       apk  = (unsigned*)(ws + 32768);       // 32 KB
    unsigned*       ank  = (unsigned*)(ws + 65536);       // 32 KB
    float*          acc2 = (float*)(ws + 98304);          // 12 B
    unsigned short* Xp   = (unsigned short*)(ws + 131072);// 8 MB

    float* out = (float*)d_out;

    prep_kernel<<<B_N / 4, 256, 0, stream>>>(X, sq, apk, ank, Xp, acc2);
    dist_kernel<<<(64 * 65) / 2, 256, 0, stream>>>(Xp, tgt, sq, apk, ank);
    final_kernel<<<B_N / 256, 256, 0, stream>>>(apk, ank, acc2, out);
}

// Round 6
// 144.301 us; speedup vs baseline: 1.8570x; 1.5794x over previous
//
#include <hip/hip_runtime.h>
#include <hip/hip_bf16.h>

#define B_N 8192
#define D_K 256
#define MARGIN 0.3f

typedef float f32x4 __attribute__((ext_vector_type(4)));
typedef short s16x8 __attribute__((ext_vector_type(8)));

// Order-preserving float->uint for atomicMax/atomicMin on floats.
__device__ __forceinline__ unsigned fkey(float f) {
    unsigned u = __float_as_uint(f);
    return (u & 0x80000000u) ? ~u : (u | 0x80000000u);
}
__device__ __forceinline__ float kval(unsigned k) {
    return (k & 0x80000000u) ? __uint_as_float(k ^ 0x80000000u)
                             : __uint_as_float(~k);
}
__device__ __forceinline__ unsigned short bfbits(float f) {
    __hip_bfloat16 h = __float2bfloat16(f);
    return *reinterpret_cast<unsigned short*>(&h);
}

// async 16B global -> LDS (width=16 variant; LDS dest = wave base + lane*16)
__device__ __forceinline__ void load_lds16(const unsigned short* g,
                                           unsigned short* l) {
    __builtin_amdgcn_global_load_lds(
        (const __attribute__((address_space(1))) unsigned int*)g,
        (__attribute__((address_space(3))) unsigned int*)l, 16, 0, 0);
}

// ---- kernel 1: norms + bf16 hi/lo split (interleaved layout) + init ------
// Xp layout: [row][chunk=k/8][hi:8 shorts | lo:8 shorts]  (row stride 512 shorts)
// 16B "unit" u (0..7 per 32-k window) = chunk_in_window*2 + (0=hi,1=lo)
__global__ __launch_bounds__(256) void prep_kernel(const float* __restrict__ X,
        float* __restrict__ sq, unsigned* __restrict__ apk,
        unsigned* __restrict__ ank, unsigned short* __restrict__ Xp,
        float* __restrict__ acc2) {
    int row  = (blockIdx.x << 2) + (threadIdx.x >> 6);
    int lane = threadIdx.x & 63;
    const float4 v = reinterpret_cast<const float4*>(X + (size_t)row * D_K)[lane];
    float s = v.x * v.x + v.y * v.y + v.z * v.z + v.w * v.w;

    float xs[4] = {v.x, v.y, v.z, v.w};
    ushort4 hv, lv;
    unsigned short* hp = &hv.x; unsigned short* lp = &lv.x;
    #pragma unroll
    for (int i = 0; i < 4; ++i) {
        __hip_bfloat16 h = __float2bfloat16(xs[i]);
        hp[i] = *reinterpret_cast<unsigned short*>(&h);
        lp[i] = bfbits(xs[i] - __bfloat162float(h));
    }
    size_t base = (size_t)row * 512 + (lane >> 1) * 16 + (lane & 1) * 4;
    *reinterpret_cast<ushort4*>(Xp + base)     = hv;   // hi half
    *reinterpret_cast<ushort4*>(Xp + base + 8) = lv;   // lo half

    #pragma unroll
    for (int o = 32; o > 0; o >>= 1) s += __shfl_down(s, o, 64);
    if (lane == 0) {
        sq[row]  = s;
        apk[row] = 0u;           // <= fkey(-inf)
        ank[row] = 0xFFFFFFFFu;  // >= fkey(+inf)
    }
    if (blockIdx.x == 0 && threadIdx.x == 0) {
        acc2[0] = 0.f; acc2[1] = 0.f;
        reinterpret_cast<unsigned*>(acc2)[2] = 0u;   // ticket counter
    }
}

// ---- kernel 2: m97-style LDS-staged MFMA dist + fused mining --------------
#define BM 128
#define BN 128
// LDS tile: 128 rows x 64 shorts (one 32-k window, hi/lo, swizzled slots)

__global__ __launch_bounds__(256, 2) void dist_kernel(
        const unsigned short* __restrict__ Xp,
        const int* __restrict__ tgt, const float* __restrict__ sq,
        unsigned* __restrict__ apk, unsigned* __restrict__ ank) {
    // triangular decode: blockIdx.x -> (bx, by), by <= bx
    int tt = blockIdx.x;
    int bx = (int)((sqrtf(8.f * (float)tt + 1.f) - 1.f) * 0.5f);
    while ((bx + 1) * (bx + 2) / 2 <= tt) ++bx;
    while (bx * (bx + 1) / 2 > tt) --bx;
    int by = tt - bx * (bx + 1) / 2;
    const int bm = by * BM;   // bm <= bn
    const int bn = bx * BN;

    __shared__ unsigned short Atile[128 * 64];   // 16 KB
    __shared__ unsigned short Btile[128 * 64];   // 16 KB

    const int t    = threadIdx.x;
    const int lane = t & 63;
    const int wave = t >> 6;
    const int wrow = (wave >> 1) * 64;
    const int wcol = (wave & 1) * 64;
    const int fr   = lane & 15;
    const int quad = lane >> 4;

    // staging precompute: thread handles global unit g = wave*64 + j*256 + lane
    // row r = g>>3, slot s = g&7 in LDS, logical unit u = s ^ (r&7) in global.
    const unsigned short* ag[4];
    const unsigned short* bg[4];
    unsigned short*       al[4];
    unsigned short*       bl[4];
    #pragma unroll
    for (int j = 0; j < 4; ++j) {
        int g = wave * 64 + j * 256 + lane;
        int r = g >> 3, s0 = g & 7;
        int u = s0 ^ (r & 7);
        ag[j] = Xp + (size_t)(bm + r) * 512 + u * 8;
        bg[j] = Xp + (size_t)(bn + r) * 512 + u * 8;
        al[j] = Atile + g * 8;   // = wave base + lane*8 shorts (16B)
        bl[j] = Btile + g * 8;
    }

    f32x4 acc[4][4];
    #pragma unroll
    for (int i = 0; i < 4; ++i)
        #pragma unroll
        for (int j = 0; j < 4; ++j) acc[i][j] = (f32x4){0.f, 0.f, 0.f, 0.f};

    #pragma unroll 1
    for (int i = 0; i < 8; ++i) {
        __syncthreads();                 // prior fragment reads complete
        const int woff = i * 64;         // window offset in shorts
        #pragma unroll
        for (int j = 0; j < 4; ++j) {
            load_lds16(ag[j] + woff, al[j]);
            load_lds16(bg[j] + woff, bl[j]);
        }
        __syncthreads();                 // staging drained (vmcnt(0) before barrier)

        s16x8 a_hi[4], a_lo[4], b_hi[4], b_lo[4];
        const int shi = (quad * 2) ^ (fr & 7);
        const int slo = shi ^ 1;
        #pragma unroll
        for (int mi = 0; mi < 4; ++mi) {
            int rb = (wrow + mi * 16 + fr) * 64;
            a_hi[mi] = *reinterpret_cast<const s16x8*>(&Atile[rb + shi * 8]);
            a_lo[mi] = *reinterpret_cast<const s16x8*>(&Atile[rb + slo * 8]);
        }
        #pragma unroll
        for (int ni = 0; ni < 4; ++ni) {
            int rb = (wcol + ni * 16 + fr) * 64;
            b_hi[ni] = *reinterpret_cast<const s16x8*>(&Btile[rb + shi * 8]);
            b_lo[ni] = *reinterpret_cast<const s16x8*>(&Btile[rb + slo * 8]);
        }
        #pragma unroll
        for (int mi = 0; mi < 4; ++mi)
            #pragma unroll
            for (int ni = 0; ni < 4; ++ni) {
                acc[mi][ni] = __builtin_amdgcn_mfma_f32_16x16x32_bf16(
                    a_hi[mi], b_hi[ni], acc[mi][ni], 0, 0, 0);
                acc[mi][ni] = __builtin_amdgcn_mfma_f32_16x16x32_bf16(
                    a_hi[mi], b_lo[ni], acc[mi][ni], 0, 0, 0);
                acc[mi][ni] = __builtin_amdgcn_mfma_f32_16x16x32_bf16(
                    a_lo[mi], b_hi[ni], acc[mi][ni], 0, 0, 0);
            }
    }

    // -------- epilogue: dist + row mining + col mining ---------------------
    const float INF = __int_as_float(0x7f800000);
    int   ct[4]; float csq[4];
    #pragma unroll
    for (int ni = 0; ni < 4; ++ni) {
        int c = bn + wcol + ni * 16 + fr;
        ct[ni] = tgt[c]; csq[ni] = sq[c];
    }
    float cap[4], can[4];
    #pragma unroll
    for (int ni = 0; ni < 4; ++ni) { cap[ni] = -INF; can[ni] = INF; }

    #pragma unroll
    for (int mi = 0; mi < 4; ++mi) {
        #pragma unroll
        for (int reg = 0; reg < 4; ++reg) {
            int rl = wrow + mi * 16 + quad * 4 + reg;
            int rt = tgt[bm + rl]; float rsq = sq[bm + rl];
            float rap = -INF, ran = INF;
            #pragma unroll
            for (int ni = 0; ni < 4; ++ni) {
                float d = rsq + csq[ni] - 2.f * acc[mi][ni][reg];
                bool pos = (rt == ct[ni]);
                if (pos) { rap = fmaxf(rap, d); cap[ni] = fmaxf(cap[ni], d); }
                else     { ran = fminf(ran, d); can[ni] = fminf(can[ni], d); }
            }
            #pragma unroll
            for (int o = 1; o < 16; o <<= 1) {
                rap = fmaxf(rap, __shfl_xor(rap, o, 64));
                ran = fminf(ran, __shfl_xor(ran, o, 64));
            }
            if (fr == 0) {
                atomicMax(&apk[bm + rl], fkey(rap));
                atomicMin(&ank[bm + rl], fkey(ran));
            }
        }
    }
    #pragma unroll
    for (int ni = 0; ni < 4; ++ni) {
        #pragma unroll
        for (int o = 16; o < 64; o <<= 1) {
            cap[ni] = fmaxf(cap[ni], __shfl_xor(cap[ni], o, 64));
            can[ni] = fminf(can[ni], __shfl_xor(can[ni], o, 64));
        }
    }
    if (lane < 16) {
        #pragma unroll
        for (int ni = 0; ni < 4; ++ni) {
            int c = bn + wcol + ni * 16 + lane;
            atomicMax(&apk[c], fkey(cap[ni]));
            atomicMin(&ank[c], fkey(can[ni]));
        }
    }
}

// ---- kernel 3: loss/prec partial sums + last-block finalize ---------------
__global__ __launch_bounds__(256) void final_kernel(const unsigned* __restrict__ apk,
        const unsigned* __restrict__ ank, float* __restrict__ acc2,
        float* __restrict__ out) {
    __shared__ float s_sum[4], s_cnt[4];
    int i = blockIdx.x * 256 + threadIdx.x;
    float ap = kval(apk[i]);
    float an = kval(ank[i]);
    float v  = ap - an + MARGIN;
    float sum = v > 0.f ? v : 0.f;
    float cnt = an > ap ? 1.f : 0.f;
    #pragma unroll
    for (int o = 32; o > 0; o >>= 1) {
        sum += __shfl_down(sum, o, 64);
        cnt += __shfl_down(cnt, o, 64);
    }
    int wave = threadIdx.x >> 6, lane = threadIdx.x & 63;
    if (lane == 0) { s_sum[wave] = sum; s_cnt[wave] = cnt; }
    __syncthreads();
    if (threadIdx.x == 0) {
        float ts = 0.f, tc = 0.f;
        #pragma unroll
        for (int w = 0; w < 4; ++w) { ts += s_sum[w]; tc += s_cnt[w]; }
        atomicAdd(&acc2[0], ts);
        atomicAdd(&acc2[1], tc);
        __threadfence();
        unsigned ticket = atomicAdd(reinterpret_cast<unsigned*>(acc2) + 2, 1u);
        if (ticket == gridDim.x - 1) {
            float fs = atomicAdd(&acc2[0], 0.f);
            float fc = atomicAdd(&acc2[1], 0.f);
            out[0] = fs / (float)B_N;
            out[1] = fc / (float)B_N;
        }
    }
}

extern "C" void kernel_launch(void* const* d_in, const int* in_sizes, int n_in,
                              void* d_out, int out_size, void* d_ws, size_t ws_size,
                              hipStream_t stream) {
    const float* X   = (const float*)d_in[0];
    const int*   tgt = (const int*)d_in[1];

    char* ws = (char*)d_ws;
    float*          sq   = (float*)ws;                    // 32 KB
    unsigned*       apk  = (unsigned*)(ws + 32768);       // 32 KB
    unsigned*       ank  = (unsigned*)(ws + 65536);       // 32 KB
    float*          acc2 = (float*)(ws + 98304);          // 12 B
    unsigned short* Xp   = (unsigned short*)(ws + 131072);// 8 MB

    float* out = (float*)d_out;

    prep_kernel<<<B_N / 4, 256, 0, stream>>>(X, sq, apk, ank, Xp, acc2);
    dist_kernel<<<(64 * 65) / 2, 256, 0, stream>>>(Xp, tgt, sq, apk, ank);
    final_kernel<<<B_N / 256, 256, 0, stream>>>(apk, ank, acc2, out);
}